// Round 14
// baseline (651.570 us; speedup 1.0000x reference)
//
#include <hip/hip_runtime.h>
#include <hip/hip_fp16.h>
#include <stdint.h>

#define K_    367
#define P_    217
#define Q_    721
#define QC    217
#define CPQ   (QC*QC)               // 47089 corner positions
#define CPQV  47092                 // corner stream stride per k (padded to /4)
#define TPQ   109368                // tail positions per k (217*504)
#define YSTR  47104                 // y plane stride (floats), 16B aligned
#define PQ_   (P_*Q_)               // 156457
#define NC    ((long long)K_*CPQ)   // 17,281,663 corner entries
#define NTAIL ((long long)K_*TPQ)   // 40,138,056 tail entries
#define SL8   (NTAIL/8)             // 5,017,257 entries per (iter,z) pack slice, exact
#define NVC   (CPQV/4)              // 11773 vec outputs (corner)
#define NVT   (TPQ/4)               // 27342 vec outputs (tail)
#define NPAD  (3*K_)                // corner pad slots
#define LDSH  47092                 // halfs in LDS (94.2 KB) -> FULL plane coverage

// entry encoding: v = (idx*2) | (f16_bits(w) << 17)   [w>=0 -> sign bit free]
__device__ __forceinline__ uint32_t encode_entry(int i0, int i1, float wv) {
    uint32_t idx2 = ((uint32_t)(i0 * QC + i1)) << 1;
    uint32_t hb = (uint32_t)__half_as_ushort(__float2half(wv));
    return idx2 | (hb << 17);
}

// branchless gather: idx-byte-offset in bits[16:1], f16 weight bits in [31:17]
#define GATHER(X, ACC) { uint32_t x_ = (X); \
    float g_ = __half2float(*(const __half*)((const char*)ylds + (x_ & 0x1FFFEu))); \
    float w_ = __half2float(__ushort_as_half((unsigned short)(x_ >> 17))); \
    ACC = fmaf(w_, g_, ACC); }

#define FILL_LDS() { \
    const float4* s4_ = (const float4*)yplane; \
    __half2* d2_ = (__half2*)ylds; \
    for (int i_ = threadIdx.x; i_ < LDSH / 4; i_ += 1024) { \
        float4 v_ = s4_[i_]; \
        d2_[2 * i_]     = __floats2half2_rn(v_.x, v_.y); \
        d2_[2 * i_ + 1] = __floats2half2_rn(v_.z, v_.w); \
    } }

// ---------- pack CORNER stream only + y0 copy + pads + zero y1..y4 + zero out.
// Tail stream is packed inside the fused iteration kernels (wave-specialized).
__global__ __launch_bounds__(256) void pack_corner(
    const int2* __restrict__ ind, const float* __restrict__ w,
    const float* __restrict__ inp,
    uint32_t* __restrict__ cornerS, float* __restrict__ ybase,
    float* __restrict__ out)
{
    long long id = (long long)blockIdx.x * 256 + threadIdx.x;
    if (id < NC) {
        uint32_t o = (uint32_t)id;
        uint32_t k = o / (uint32_t)CPQ;           // magic-mul
        uint32_t r = o - k * (uint32_t)CPQ;
        uint32_t p = r / (uint32_t)QC;
        uint32_t q = r - p * (uint32_t)QC;
        long long raw = (long long)k * PQ_ + p * Q_ + q;
        unsigned long long rr =
            __builtin_nontemporal_load((const unsigned long long*)(ind + raw));
        float wv = __builtin_nontemporal_load(w + raw);
        cornerS[k * (uint32_t)CPQV + r] =
            encode_entry((int)(uint32_t)(rr & 0xFFFFFFFFull),
                         (int)(uint32_t)(rr >> 32), wv);
        return;
    }
    long long e = id - NC;
    if (e < CPQ) {                                // y0 corner copy (both batches)
        int o = (int)e;
        int p = o / QC, q = o - p * QC;
        ybase[o]        = inp[p * 256 + q];
        ybase[YSTR + o] = inp[65536 + p * 256 + q];
        return;
    }
    e -= CPQ;
    if (e < NPAD) {                               // pad slots: idx=0, w=+0 -> no-op
        int k = (int)(e / 3);
        cornerS[(long long)k * CPQV + CPQ + (int)(e - (long long)k * 3)] = 0u;
        return;
    }
    e -= NPAD;
    if (e < 8 * YSTR) {                           // zero y1..y4 (atomic targets)
        ybase[2 * YSTR + e] = 0.f;
        return;
    }
    e -= 8 * YSTR;
    if (e < 2 * PQ_) out[e] = 0.f;                // zero output
}

// ---------- fused corner iteration: WAVE-SPECIALIZED.
// grid (240,1,2), 1024 thr. Warps 0..11 (768 thr): corner gather (LDS pipe).
// Warps 12..15 (256 thr): pack tail slice (it*2+bz)/8 (VMEM pipe). The two
// roles co-issue on each CU -> tail-pack time hides under the gather.
// Gather units: ob = bid%16 (chunks of 768 vec-units), kc = bid/16, KS=15.
__global__ __launch_bounds__(1024) void iter_fused(
    const uint32_t* __restrict__ cs,
    const int2* __restrict__ ind, const float* __restrict__ w,
    uint32_t* __restrict__ tailS,
    const float* __restrict__ yin, float* __restrict__ yout,
    const float* __restrict__ lam_p, int it)
{
    __shared__ __half ylds[LDSH];
    const int bz = blockIdx.z;
    const float* __restrict__ yplane = yin + (size_t)bz * YSTR;
    FILL_LDS();
    __syncthreads();

    if (threadIdx.x < 768) {
        // ---- gather role (12 waves)
        const float ls = *lam_p;
        int ob = blockIdx.x % 16, kc = blockIdx.x / 16;   // KS = 15
        int k0 = kc * K_ / 15, k1 = (kc + 1) * K_ / 15;
        int ov = ob * 768 + threadIdx.x;
        if (ov < NVC) {
            float a0 = 0.f, a1 = 0.f, a2 = 0.f, a3 = 0.f;
            const uint4* pp = (const uint4*)cs + (long long)k0 * NVC + ov;
            #pragma unroll 8
            for (int k = k0; k < k1; ++k, pp += NVC) {
                uint4 v = *pp;
                GATHER(v.x, a0); GATHER(v.y, a1); GATHER(v.z, a2); GATHER(v.w, a3);
            }
            float* op = yout + (size_t)bz * YSTR + 4 * ov;
            atomicAdd(op + 0, a0 * ls);
            atomicAdd(op + 1, a1 * ls);
            atomicAdd(op + 2, a2 * ls);
            atomicAdd(op + 3, a3 * ls);
        }
    } else {
        // ---- tail-pack role (4 waves): slice s = it*2 + bz of 8, dense runs
        long long t0 = (long long)(it * 2 + bz) * SL8;
        long long t1 = t0 + SL8;
        int lw = threadIdx.x - 768;                        // 0..255
        for (long long t = t0 + (long long)blockIdx.x * 256 + lw; t < t1;
             t += 240LL * 256) {
            uint32_t tt = (uint32_t)t;
            uint32_t k = tt / (uint32_t)TPQ;               // magic-mul
            uint32_t r = tt - k * (uint32_t)TPQ;
            uint32_t p = r / 504u;
            uint32_t q2 = r - p * 504u;
            long long raw = (long long)k * PQ_ + p * Q_ + QC + q2;
            unsigned long long rr =
                __builtin_nontemporal_load((const unsigned long long*)(ind + raw));
            float wv = __builtin_nontemporal_load(w + raw);
            tailS[tt] = encode_entry((int)(uint32_t)(rr & 0xFFFFFFFFull),
                                     (int)(uint32_t)(rr >> 32), wv);
        }
    }
}

// ---------- final iteration (R9-proven): corner + tail packed streams.
// grid: (117, 1, 2); nunits = 39*KS(6) = 234 -> exactly 2 units per block.
__global__ __launch_bounds__(1024) void iter_final(
    const uint32_t* __restrict__ cs, const uint32_t* __restrict__ ts,
    const float* __restrict__ yin, float* __restrict__ out,
    const float* __restrict__ lam_p, int KS)
{
    __shared__ __half ylds[LDSH];
    const int bz = blockIdx.z;
    const float* __restrict__ yplane = yin + (size_t)bz * YSTR;
    FILL_LDS();
    __syncthreads();
    const int NV = NVC + NVT;
    const int gx = (NV + 1023) / 1024;
    const int nunits = gx * KS;
    const float ls = *lam_p;
    for (int unit = blockIdx.x; unit < nunits; unit += gridDim.x) {
        int ob = unit % gx, kc = unit / gx;
        int ov = ob * 1024 + threadIdx.x;
        if (ov >= NV) continue;
        bool corner = ov < NVC;
        int lv = corner ? ov : ov - NVC;
        int stride = corner ? NVC : NVT;
        const uint4* base = corner ? (const uint4*)cs : (const uint4*)ts;
        int k0 = kc * K_ / KS, k1 = (kc + 1) * K_ / KS;
        float a0 = 0.f, a1 = 0.f, a2 = 0.f, a3 = 0.f;
        const uint4* pp = base + (long long)k0 * stride + lv;
        #pragma unroll 8
        for (int k = k0; k < k1; ++k, pp += stride) {
            uint4 v = *pp;
            GATHER(v.x, a0); GATHER(v.y, a1); GATHER(v.z, a2); GATHER(v.w, a3);
        }
        float acc[4] = {a0, a1, a2, a3};
        int o0 = 4 * lv;
        #pragma unroll
        for (int j = 0; j < 4; ++j) {
            int oo = o0 + j;
            int pos;
            if (corner) {
                if (oo >= CPQ) continue;          // pad slot
                int p = oo / QC; pos = p * Q_ + (oo - p * QC);
            } else {
                int p = oo / 504; pos = p * Q_ + QC + (oo - p * 504);
            }
            atomicAdd(&out[(size_t)bz * PQ_ + pos], acc[j] * ls);
        }
    }
}

extern "C" void kernel_launch(void* const* d_in, const int* in_sizes, int n_in,
                              void* d_out, int out_size, void* d_ws, size_t ws_size,
                              hipStream_t stream)
{
    const float* inp = (const float*)d_in[0];
    const int2*  ind = (const int2*)d_in[1];
    const float* w1  = (const float*)d_in[2];
    const float* lam = (const float*)d_in[3];
    float* out = (float*)d_out;

    size_t cbytes = ((((size_t)K_ * CPQV) * 4) + 255) & ~(size_t)255;
    size_t tbytes = ((((size_t)NTAIL) * 4) + 255) & ~(size_t)255;
    size_t YB = (size_t)(2 * YSTR) * sizeof(float);
    if (ws_size < cbytes + tbytes + 5 * YB) return;   // ws has always been ample

    uint8_t* ws = (uint8_t*)d_ws;
    uint32_t* cornerS = (uint32_t*)ws;
    uint32_t* tailS   = (uint32_t*)(ws + cbytes);
    float* ybase = (float*)(ws + cbytes + tbytes);
    float* y[5];
    for (int i = 0; i < 5; ++i) y[i] = ybase + (size_t)i * (2 * YSTR);

    // setup: corner pack + y0 copy + pads + zero y1..y4 + zero out
    long long nwork = NC + CPQ + NPAD + 8LL * YSTR + 2LL * PQ_;
    unsigned nb = (unsigned)((nwork + 255) / 256);
    pack_corner<<<dim3(nb), 256, 0, stream>>>(ind, w1, inp, cornerS, ybase, out);

    // 4 fused iterations: 12 gather waves + 4 tail-pack waves per block
    dim3 gC(240, 1, 2), gF(117, 1, 2);
    for (int it = 0; it < 4; ++it)
        iter_fused<<<gC, 1024, 0, stream>>>(cornerS, ind, w1, tailS,
                                            y[it], y[it + 1], lam, it);
    iter_final<<<gF, 1024, 0, stream>>>(cornerS, tailS, y[4], out, lam, 6);
}

// Round 15
// 362.441 us; speedup vs baseline: 1.7977x; 1.7977x over previous
//
#include <hip/hip_runtime.h>
#include <hip/hip_fp16.h>
#include <stdint.h>

#define K_    367
#define P_    217
#define Q_    721
#define QC    217
#define CPQ   (QC*QC)               // 47089 corner positions
#define CPQV  47092                 // corner stream stride per k (padded to /4)
#define TPQ   109368                // tail positions per k (217*504)
#define YSTR  47104                 // y plane stride (floats), 16B aligned
#define PQ_   (P_*Q_)               // 156457
#define TOT   ((long long)K_*PQ_)   // 57,419,719 entries (odd)
#define HALF_ ((TOT+1)/2)           // 28,709,860
#define NVC   (CPQV/4)              // 11773 vec outputs (corner)
#define NVT   (TPQ/4)               // 27342 vec outputs (tail)
#define NPAD  (3*K_)                // corner pad slots
#define LDSH  47092                 // halfs in LDS (94.2 KB) -> FULL plane coverage

// entry encoding: v = (idx*2) | (f16_bits(w) << 17)   [w>=0 -> sign bit free]
__device__ __forceinline__ uint32_t encode_entry(int i0, int i1, float wv) {
    uint32_t idx2 = ((uint32_t)(i0 * QC + i1)) << 1;
    uint32_t hb = (uint32_t)__half_as_ushort(__float2half(wv));
    return idx2 | (hb << 17);
}
__device__ __forceinline__ void store_entry(uint32_t ui, uint32_t v,
    uint32_t* __restrict__ cornerS, uint32_t* __restrict__ tailS) {
    uint32_t k = ui / (uint32_t)PQ_;          // magic-mul div
    uint32_t rem = ui - k * (uint32_t)PQ_;
    uint32_t p = rem / (uint32_t)Q_;
    uint32_t q = rem - p * (uint32_t)Q_;
    if (q < QC) cornerS[k * (uint32_t)CPQV + p * QC + q] = v;                  // run 217
    else        tailS[(long long)k * TPQ + p * 504 + (q - QC)] = v;            // run 504
}

// branchless gather: idx-byte-offset in bits[16:1], f16 weight bits in [31:17]
#define GATHER(X, ACC) { uint32_t x_ = (X); \
    float g_ = __half2float(*(const __half*)((const char*)ylds + (x_ & 0x1FFFEu))); \
    float w_ = __half2float(__ushort_as_half((unsigned short)(x_ >> 17))); \
    ACC = fmaf(w_, g_, ACC); }

#define FILL_LDS() { \
    const float4* s4_ = (const float4*)yplane; \
    __half2* d2_ = (__half2*)ylds; \
    for (int i_ = threadIdx.x; i_ < LDSH / 4; i_ += 1024) { \
        float4 v_ = s4_[i_]; \
        d2_[2 * i_]     = __floats2half2_rn(v_.x, v_.y); \
        d2_[2 * i_ + 1] = __floats2half2_rn(v_.z, v_.w); \
    } }

// ---------- pack: 2 entries/thread at (id, id+HALF_), dense stride-1 loads and
// stores within each wave. A/B CHANGE vs R9: plain CACHED loads (nt removed) —
// testing whether nt was capping streaming read BW (m13's 6.3 TB/s was cached).
// Also folds: y0 corner copy, corner pad slots, y1..y4 zero, out zero.
__global__ __launch_bounds__(256) void pack_all(
    const int2* __restrict__ ind, const float* __restrict__ w,
    const float* __restrict__ inp,
    uint32_t* __restrict__ cornerS, uint32_t* __restrict__ tailS,
    float* __restrict__ ybase, float* __restrict__ out)
{
    long long id = (long long)blockIdx.x * 256 + threadIdx.x;
    if (id < HALF_) {
        // entry e0 = id  (dense across lanes)
        unsigned long long r0 = *(const unsigned long long*)(ind + id);
        float w0 = w[id];
        store_entry((uint32_t)id,
                    encode_entry((int)(uint32_t)(r0 & 0xFFFFFFFFull),
                                 (int)(uint32_t)(r0 >> 32), w0),
                    cornerS, tailS);
        // entry e1 = id + HALF_  (dense across lanes)
        long long e1 = id + HALF_;
        if (e1 < TOT) {
            unsigned long long r1 = *(const unsigned long long*)(ind + e1);
            float w1v = w[e1];
            store_entry((uint32_t)e1,
                        encode_entry((int)(uint32_t)(r1 & 0xFFFFFFFFull),
                                     (int)(uint32_t)(r1 >> 32), w1v),
                        cornerS, tailS);
        }
        return;
    }
    long long e = id - HALF_;
    if (e < CPQ) {                                // y0 corner copy (both batches)
        int o = (int)e;
        int p = o / QC, q = o - p * QC;
        ybase[o]        = inp[p * 256 + q];
        ybase[YSTR + o] = inp[65536 + p * 256 + q];
        return;
    }
    e -= CPQ;
    if (e < NPAD) {                               // pad slots: idx=0, w=+0 -> no-op
        int k = (int)(e / 3);
        cornerS[(long long)k * CPQV + CPQ + (int)(e - (long long)k * 3)] = 0u;
        return;
    }
    e -= NPAD;
    if (e < 8 * YSTR) {                           // zero y1..y4 (atomic targets)
        ybase[2 * YSTR + e] = 0.f;
        return;
    }
    e -= 8 * YSTR;
    if (e < 2 * PQ_) out[e] = 0.f;                // zero output
}

// ---------- corner iteration (R9-proven, unchanged)
// grid: (120, 1, 2); nunits = 12*KS(10) = 120 -> exactly 1 unit per block.
__global__ __launch_bounds__(1024) void iter_corner(
    const uint32_t* __restrict__ cs, const float* __restrict__ yin,
    float* __restrict__ yout, const float* __restrict__ lam_p, int KS)
{
    __shared__ __half ylds[LDSH];
    const int bz = blockIdx.z;
    const float* __restrict__ yplane = yin + (size_t)bz * YSTR;
    FILL_LDS();
    __syncthreads();
    const int gx = (NVC + 1023) / 1024;
    const int nunits = gx * KS;
    const float ls = *lam_p;
    const uint4* cs4 = (const uint4*)cs;
    for (int unit = blockIdx.x; unit < nunits; unit += gridDim.x) {
        int ob = unit % gx, kc = unit / gx;
        int ov = ob * 1024 + threadIdx.x;
        if (ov >= NVC) continue;
        int k0 = kc * K_ / KS, k1 = (kc + 1) * K_ / KS;
        float a0 = 0.f, a1 = 0.f, a2 = 0.f, a3 = 0.f;
        const uint4* pp = cs4 + (long long)k0 * NVC + ov;
        #pragma unroll 8
        for (int k = k0; k < k1; ++k, pp += NVC) {
            uint4 v = *pp;
            GATHER(v.x, a0); GATHER(v.y, a1); GATHER(v.z, a2); GATHER(v.w, a3);
        }
        float* op = yout + (size_t)bz * YSTR + 4 * ov;
        atomicAdd(op + 0, a0 * ls);
        atomicAdd(op + 1, a1 * ls);
        atomicAdd(op + 2, a2 * ls);
        atomicAdd(op + 3, a3 * ls);
    }
}

// ---------- final iteration (R9-proven, unchanged)
// grid: (117, 1, 2); nunits = 39*KS(6) = 234 -> exactly 2 units per block.
__global__ __launch_bounds__(1024) void iter_final(
    const uint32_t* __restrict__ cs, const uint32_t* __restrict__ ts,
    const float* __restrict__ yin, float* __restrict__ out,
    const float* __restrict__ lam_p, int KS)
{
    __shared__ __half ylds[LDSH];
    const int bz = blockIdx.z;
    const float* __restrict__ yplane = yin + (size_t)bz * YSTR;
    FILL_LDS();
    __syncthreads();
    const int NV = NVC + NVT;
    const int gx = (NV + 1023) / 1024;
    const int nunits = gx * KS;
    const float ls = *lam_p;
    for (int unit = blockIdx.x; unit < nunits; unit += gridDim.x) {
        int ob = unit % gx, kc = unit / gx;
        int ov = ob * 1024 + threadIdx.x;
        if (ov >= NV) continue;
        bool corner = ov < NVC;
        int lv = corner ? ov : ov - NVC;
        int stride = corner ? NVC : NVT;
        const uint4* base = corner ? (const uint4*)cs : (const uint4*)ts;
        int k0 = kc * K_ / KS, k1 = (kc + 1) * K_ / KS;
        float a0 = 0.f, a1 = 0.f, a2 = 0.f, a3 = 0.f;
        const uint4* pp = base + (long long)k0 * stride + lv;
        #pragma unroll 8
        for (int k = k0; k < k1; ++k, pp += stride) {
            uint4 v = *pp;
            GATHER(v.x, a0); GATHER(v.y, a1); GATHER(v.z, a2); GATHER(v.w, a3);
        }
        float acc[4] = {a0, a1, a2, a3};
        int o0 = 4 * lv;
        #pragma unroll
        for (int j = 0; j < 4; ++j) {
            int oo = o0 + j;
            int pos;
            if (corner) {
                if (oo >= CPQ) continue;          // pad slot
                int p = oo / QC; pos = p * Q_ + (oo - p * QC);
            } else {
                int p = oo / 504; pos = p * Q_ + QC + (oo - p * 504);
            }
            atomicAdd(&out[(size_t)bz * PQ_ + pos], acc[j] * ls);
        }
    }
}

extern "C" void kernel_launch(void* const* d_in, const int* in_sizes, int n_in,
                              void* d_out, int out_size, void* d_ws, size_t ws_size,
                              hipStream_t stream)
{
    const float* inp = (const float*)d_in[0];
    const int2*  ind = (const int2*)d_in[1];
    const float* w1  = (const float*)d_in[2];
    const float* lam = (const float*)d_in[3];
    float* out = (float*)d_out;

    size_t cbytes = ((((size_t)K_ * CPQV) * 4) + 255) & ~(size_t)255;
    size_t tbytes = ((((size_t)K_ * TPQ) * 4) + 255) & ~(size_t)255;
    size_t YB = (size_t)(2 * YSTR) * sizeof(float);
    if (ws_size < cbytes + tbytes + 5 * YB) return;   // ws has always been ample

    uint8_t* ws = (uint8_t*)d_ws;
    uint32_t* cornerS = (uint32_t*)ws;
    uint32_t* tailS   = (uint32_t*)(ws + cbytes);
    float* ybase = (float*)(ws + cbytes + tbytes);
    float* y[5];
    for (int i = 0; i < 5; ++i) y[i] = ybase + (size_t)i * (2 * YSTR);

    // single setup dispatch: pack both streams + y0 copy + pads + zero y1..y4 + out
    long long nwork = HALF_ + CPQ + NPAD + 8LL * YSTR + 2LL * PQ_;
    unsigned nb = (unsigned)((nwork + 255) / 256);
    pack_all<<<dim3(nb), 256, 0, stream>>>(ind, w1, inp, cornerS, tailS, ybase, out);

    dim3 gC(120, 1, 2), gF(117, 1, 2);
    for (int it = 0; it < 4; ++it)
        iter_corner<<<gC, 1024, 0, stream>>>(cornerS, y[it], y[it + 1], lam, 10);
    iter_final<<<gF, 1024, 0, stream>>>(cornerS, tailS, y[4], out, lam, 6);
}

// Round 16
// 343.833 us; speedup vs baseline: 1.8950x; 1.0541x over previous
//
#include <hip/hip_runtime.h>
#include <hip/hip_fp16.h>
#include <stdint.h>

#define K_    367
#define P_    217
#define Q_    721
#define QC    217
#define CPQ   (QC*QC)               // 47089 corner positions
#define CPQV  47092                 // corner stream stride per k (padded to /4)
#define TPQ   109368                // tail positions per k (217*504), /4 ok
#define YSTR  47104                 // y plane stride (floats), 16B aligned
#define PQ_   (P_*Q_)               // 156457
#define TOT   ((long long)K_*PQ_)   // 57,419,719 entries (odd)
#define NPAIR (TOT/2)               // 28,709,859 pairs
#define NVC   (CPQV/4)              // 11773 vec outputs (corner)
#define NVT   (TPQ/4)               // 27342 vec outputs (tail)
#define NPAD  (3*K_)                // corner pad slots
#define LDSH  47092                 // halfs in LDS (94.2 KB) -> FULL plane coverage

// native clang vectors: __builtin_nontemporal_load accepts these (not HIP_vector_type)
typedef uint32_t u32x4 __attribute__((ext_vector_type(4)));
typedef float    f32x2 __attribute__((ext_vector_type(2)));

// entry encoding: v = (idx*2) | (f16_bits(w) << 17)   [w>=0 -> sign bit free]
__device__ __forceinline__ uint32_t encode_entry(int i0, int i1, float wv) {
    uint32_t idx2 = ((uint32_t)(i0 * QC + i1)) << 1;
    uint32_t hb = (uint32_t)__half_as_ushort(__float2half(wv));
    return idx2 | (hb << 17);
}
__device__ __forceinline__ void store_entry(uint32_t ui, uint32_t v,
    uint32_t* __restrict__ cornerS, uint32_t* __restrict__ tailS) {
    uint32_t k = ui / (uint32_t)PQ_;          // magic-mul div
    uint32_t rem = ui - k * (uint32_t)PQ_;
    uint32_t p = rem / (uint32_t)Q_;
    uint32_t q = rem - p * (uint32_t)Q_;
    if (q < QC) cornerS[k * (uint32_t)CPQV + p * QC + q] = v;                  // run 217
    else        tailS[(long long)k * TPQ + p * 504 + (q - QC)] = v;            // run 504
}

// branchless gather: idx-byte-offset in bits[16:1], f16 weight bits in [31:17]
#define GATHER(X, ACC) { uint32_t x_ = (X); \
    float g_ = __half2float(*(const __half*)((const char*)ylds + (x_ & 0x1FFFEu))); \
    float w_ = __half2float(__ushort_as_half((unsigned short)(x_ >> 17))); \
    ACC = fmaf(w_, g_, ACC); }

#define FILL_LDS() { \
    const float4* s4_ = (const float4*)yplane; \
    __half2* d2_ = (__half2*)ylds; \
    for (int i_ = threadIdx.x; i_ < LDSH / 4; i_ += 1024) { \
        float4 v_ = s4_[i_]; \
        d2_[2 * i_]     = __floats2half2_rn(v_.x, v_.y); \
        d2_[2 * i_ + 1] = __floats2half2_rn(v_.z, v_.w); \
    } }

// ---------- pack (2 consecutive entries/thread, nt vector loads) + y0 copy +
// pads + zero fills. CHAMPION VARIANT (benched 345 us in round 9).
__global__ __launch_bounds__(256) void pack_all(
    const int2* __restrict__ ind, const float* __restrict__ w,
    const float* __restrict__ inp,
    uint32_t* __restrict__ cornerS, uint32_t* __restrict__ tailS,
    float* __restrict__ ybase, float* __restrict__ out)
{
    long long id = (long long)blockIdx.x * 256 + threadIdx.x;
    if (id < NPAIR) {
        long long i = id * 2;
        u32x4 r  = __builtin_nontemporal_load((const u32x4*)(ind + i));   // 16B
        f32x2 wv = __builtin_nontemporal_load((const f32x2*)(w + i));     // 8B
        uint32_t v0 = encode_entry((int)r.x, (int)r.y, wv.x);
        uint32_t v1 = encode_entry((int)r.z, (int)r.w, wv.y);
        store_entry((uint32_t)i,      v0, cornerS, tailS);
        store_entry((uint32_t)i + 1u, v1, cornerS, tailS);
        return;
    }
    if (id == NPAIR) {                            // TOT is odd: last entry
        long long i = TOT - 1;
        int2 e = ind[i];
        store_entry((uint32_t)i, encode_entry(e.x, e.y, w[i]), cornerS, tailS);
        return;
    }
    long long e = id - (NPAIR + 1);
    if (e < CPQ) {                                // y0 corner copy (both batches)
        int o = (int)e;
        int p = o / QC, q = o - p * QC;
        ybase[o]        = inp[p * 256 + q];
        ybase[YSTR + o] = inp[65536 + p * 256 + q];
        return;
    }
    e -= CPQ;
    if (e < NPAD) {                               // pad slots: idx=0, w=+0 -> no-op
        int k = (int)(e / 3);
        cornerS[(long long)k * CPQV + CPQ + (int)(e - (long long)k * 3)] = 0u;
        return;
    }
    e -= NPAD;
    if (e < 8 * YSTR) {                           // zero y1..y4 (atomic targets)
        ybase[2 * YSTR + e] = 0.f;
        return;
    }
    e -= 8 * YSTR;
    if (e < 2 * PQ_) out[e] = 0.f;                // zero output
}

// ---------- corner iteration: vec-4 over contiguous corner stream.
// grid: (120, 1, 2); nunits = 12*KS(10) = 120 -> exactly 1 unit per block.
__global__ __launch_bounds__(1024) void iter_corner(
    const uint32_t* __restrict__ cs, const float* __restrict__ yin,
    float* __restrict__ yout, const float* __restrict__ lam_p, int KS)
{
    __shared__ __half ylds[LDSH];
    const int bz = blockIdx.z;
    const float* __restrict__ yplane = yin + (size_t)bz * YSTR;
    FILL_LDS();
    __syncthreads();
    const int gx = (NVC + 1023) / 1024;
    const int nunits = gx * KS;
    const float ls = *lam_p;
    const uint4* cs4 = (const uint4*)cs;
    for (int unit = blockIdx.x; unit < nunits; unit += gridDim.x) {
        int ob = unit % gx, kc = unit / gx;
        int ov = ob * 1024 + threadIdx.x;
        if (ov >= NVC) continue;
        int k0 = kc * K_ / KS, k1 = (kc + 1) * K_ / KS;
        float a0 = 0.f, a1 = 0.f, a2 = 0.f, a3 = 0.f;
        const uint4* pp = cs4 + (long long)k0 * NVC + ov;
        #pragma unroll 8
        for (int k = k0; k < k1; ++k, pp += NVC) {
            uint4 v = *pp;
            GATHER(v.x, a0); GATHER(v.y, a1); GATHER(v.z, a2); GATHER(v.w, a3);
        }
        float* op = yout + (size_t)bz * YSTR + 4 * ov;
        atomicAdd(op + 0, a0 * ls);
        atomicAdd(op + 1, a1 * ls);
        atomicAdd(op + 2, a2 * ls);
        atomicAdd(op + 3, a3 * ls);
    }
}

// ---------- final iteration: corner half from corner stream, tail from tail stream.
// grid: (117, 1, 2); nunits = 39*KS(6) = 234 -> exactly 2 units per block.
__global__ __launch_bounds__(1024) void iter_final(
    const uint32_t* __restrict__ cs, const uint32_t* __restrict__ ts,
    const float* __restrict__ yin, float* __restrict__ out,
    const float* __restrict__ lam_p, int KS)
{
    __shared__ __half ylds[LDSH];
    const int bz = blockIdx.z;
    const float* __restrict__ yplane = yin + (size_t)bz * YSTR;
    FILL_LDS();
    __syncthreads();
    const int NV = NVC + NVT;
    const int gx = (NV + 1023) / 1024;
    const int nunits = gx * KS;
    const float ls = *lam_p;
    for (int unit = blockIdx.x; unit < nunits; unit += gridDim.x) {
        int ob = unit % gx, kc = unit / gx;
        int ov = ob * 1024 + threadIdx.x;
        if (ov >= NV) continue;
        bool corner = ov < NVC;
        int lv = corner ? ov : ov - NVC;
        int stride = corner ? NVC : NVT;
        const uint4* base = corner ? (const uint4*)cs : (const uint4*)ts;
        int k0 = kc * K_ / KS, k1 = (kc + 1) * K_ / KS;
        float a0 = 0.f, a1 = 0.f, a2 = 0.f, a3 = 0.f;
        const uint4* pp = base + (long long)k0 * stride + lv;
        #pragma unroll 8
        for (int k = k0; k < k1; ++k, pp += stride) {
            uint4 v = *pp;
            GATHER(v.x, a0); GATHER(v.y, a1); GATHER(v.z, a2); GATHER(v.w, a3);
        }
        float acc[4] = {a0, a1, a2, a3};
        int o0 = 4 * lv;
        #pragma unroll
        for (int j = 0; j < 4; ++j) {
            int oo = o0 + j;
            int pos;
            if (corner) {
                if (oo >= CPQ) continue;          // pad slot
                int p = oo / QC; pos = p * Q_ + (oo - p * QC);
            } else {
                int p = oo / 504; pos = p * Q_ + QC + (oo - p * 504);
            }
            atomicAdd(&out[(size_t)bz * PQ_ + pos], acc[j] * ls);
        }
    }
}

extern "C" void kernel_launch(void* const* d_in, const int* in_sizes, int n_in,
                              void* d_out, int out_size, void* d_ws, size_t ws_size,
                              hipStream_t stream)
{
    const float* inp = (const float*)d_in[0];
    const int2*  ind = (const int2*)d_in[1];
    const float* w1  = (const float*)d_in[2];
    const float* lam = (const float*)d_in[3];
    float* out = (float*)d_out;

    size_t cbytes = ((((size_t)K_ * CPQV) * 4) + 255) & ~(size_t)255;
    size_t tbytes = ((((size_t)K_ * TPQ) * 4) + 255) & ~(size_t)255;
    size_t YB = (size_t)(2 * YSTR) * sizeof(float);
    if (ws_size < cbytes + tbytes + 5 * YB) return;   // ws has always been ample

    uint8_t* ws = (uint8_t*)d_ws;
    uint32_t* cornerS = (uint32_t*)ws;
    uint32_t* tailS   = (uint32_t*)(ws + cbytes);
    float* ybase = (float*)(ws + cbytes + tbytes);
    float* y[5];
    for (int i = 0; i < 5; ++i) y[i] = ybase + (size_t)i * (2 * YSTR);

    // single setup dispatch: pack both streams + y0 copy + pads + zero y1..y4 + out
    long long nwork = NPAIR + 1 + CPQ + NPAD + 8LL * YSTR + 2LL * PQ_;
    unsigned nb = (unsigned)((nwork + 255) / 256);
    pack_all<<<dim3(nb), 256, 0, stream>>>(ind, w1, inp, cornerS, tailS, ybase, out);

    dim3 gC(120, 1, 2), gF(117, 1, 2);
    for (int it = 0; it < 4; ++it)
        iter_corner<<<gC, 1024, 0, stream>>>(cornerS, y[it], y[it + 1], lam, 10);
    iter_final<<<gF, 1024, 0, stream>>>(cornerS, tailS, y[4], out, lam, 6);
}